// Round 8
// baseline (238.611 us; speedup 1.0000x reference)
//
#include <hip/hip_runtime.h>
#include <hip/hip_bf16.h>

#define DIN 128

typedef __attribute__((ext_vector_type(8))) short short8;
typedef __attribute__((ext_vector_type(4))) float f32x4;
typedef __attribute__((ext_vector_type(4))) unsigned short ushort4v;
typedef __attribute__((ext_vector_type(8))) unsigned short ushort8v;

__device__ __forceinline__ unsigned short f2bf(float f) {
    unsigned int u = __float_as_uint(f);
    u += 0x7FFFu + ((u >> 16) & 1u);   // RNE
    return (unsigned short)(u >> 16);
}
__device__ __forceinline__ float bflo(unsigned int v) { return __uint_as_float(v << 16); }
__device__ __forceinline__ float bfhi(unsigned int v) { return __uint_as_float(v & 0xFFFF0000u); }

// ================= dtype conversion =================
__global__ __launch_bounds__(256) void convert_x_kernel(const float* __restrict__ x,
                                                        unsigned short* __restrict__ xb,
                                                        int total4) {
    int i = blockIdx.x * 256 + threadIdx.x;
    if (i < total4) {
        float4 v = reinterpret_cast<const float4*>(x)[i];
        ushort4v o = {f2bf(v.x), f2bf(v.y), f2bf(v.z), f2bf(v.w)};
        reinterpret_cast<ushort4v*>(xb)[i] = o;
    }
}

// pack [Wl|Wr] into MFMA-fragment-ordered bf16 (chunk (nt,ks): 64 lanes x 8 bf16)
template <int DOUT>
__global__ __launch_bounds__(256) void pack_w_kernel(const float* __restrict__ Wl,
                                                     const float* __restrict__ Wr,
                                                     unsigned short* __restrict__ Wp) {
    constexpr int NT = DOUT / 16;
    int idx = blockIdx.x * 256 + threadIdx.x;
    if (idx >= NT * 8 * 64) return;
    int l = idx & 63;
    int ts = idx >> 6;
    int ks = ts & 7;
    int nt = ts >> 3;
    int row = nt * 16 + (l & 15);
    int k = ks * 32 + ((l >> 4) << 3);
    const float* s = (k < 128) ? (Wl + (size_t)row * 128 + k)
                               : (Wr + (size_t)row * 128 + (k - 128));
    float4 v0 = *reinterpret_cast<const float4*>(s);
    float4 v1 = *reinterpret_cast<const float4*>(s + 4);
    unsigned short* d = Wp + (size_t)idx * 8;
    ushort4v o0 = {f2bf(v0.x), f2bf(v0.y), f2bf(v0.z), f2bf(v0.w)};
    ushort4v o1 = {f2bf(v1.x), f2bf(v1.y), f2bf(v1.z), f2bf(v1.w)};
    *reinterpret_cast<ushort4v*>(d) = o0;
    *reinterpret_cast<ushort4v*>(d + 4) = o1;
}

// ================= CSR build =================
__global__ __launch_bounds__(256) void hist_kernel(const int* __restrict__ dst,
                                                   int* __restrict__ deg, int E) {
    int E4 = E >> 2;
    int i = blockIdx.x * 256 + threadIdx.x;
    if (i < E4) {
        int4 d = reinterpret_cast<const int4*>(dst)[i];
        atomicAdd(&deg[d.x], 1);
        atomicAdd(&deg[d.y], 1);
        atomicAdd(&deg[d.z], 1);
        atomicAdd(&deg[d.w], 1);
    } else {
        int e = (E4 << 2) + (i - E4);
        if (i >= E4 && e < E) atomicAdd(&deg[dst[e]], 1);
    }
}

__global__ __launch_bounds__(256) void scan1_kernel(const int* __restrict__ deg,
                                                    int* __restrict__ excl,
                                                    int* __restrict__ bsum, int n) {
    __shared__ int s[256];
    int t = threadIdx.x;
    int i = blockIdx.x * 256 + t;
    int v = (i < n) ? deg[i] : 0;
    s[t] = v;
    __syncthreads();
    for (int off = 1; off < 256; off <<= 1) {
        int add = (t >= off) ? s[t - off] : 0;
        __syncthreads();
        s[t] += add;
        __syncthreads();
    }
    if (i < n) excl[i] = s[t] - v;
    if (t == 255) bsum[blockIdx.x] = s[255];
}

__global__ __launch_bounds__(256) void scan2_kernel(const int* __restrict__ bsum,
                                                    int* __restrict__ boff, int nb) {
    __shared__ int s[256];
    int t = threadIdx.x;
    int v = (t < nb) ? bsum[t] : 0;
    s[t] = v;
    __syncthreads();
    for (int off = 1; off < 256; off <<= 1) {
        int add = (t >= off) ? s[t - off] : 0;
        __syncthreads();
        s[t] += add;
        __syncthreads();
    }
    if (t < nb) boff[t] = s[t] - v;
}

// row_ptr + per-bucket cursor init (bucket b = nodes [b*256, b*256+256))
__global__ __launch_bounds__(256) void scan3_kernel(const int* __restrict__ excl,
                                                    const int* __restrict__ boff,
                                                    int* __restrict__ row_ptr,
                                                    int* __restrict__ bcur, int n, int E) {
    int i = blockIdx.x * 256 + threadIdx.x;
    if (i < n) {
        int r = excl[i] + boff[i >> 8];
        row_ptr[i] = r;
        if ((i & 255) == 0) bcur[i >> 8] = r;
    }
    if (i == n) row_ptr[n] = E;
}

// phase A: per-block LDS bucket histogram -> one global range-claim per (block,bucket)
#define CHUNK 4096
__global__ __launch_bounds__(256) void chunk_scatter_kernel(const int* __restrict__ src,
                                                            const int* __restrict__ dst,
                                                            int* __restrict__ bcur,
                                                            unsigned int* __restrict__ tmp,
                                                            int E) {
    __shared__ int hist[256];
    __shared__ int base[256];
    int t = threadIdx.x;
    int e0 = blockIdx.x * CHUNK;
    int e1 = min(e0 + CHUNK, E);
    hist[t] = 0;
    __syncthreads();
    for (int e = e0 + t; e < e1; e += 256) {
        atomicAdd(&hist[dst[e] >> 8], 1);   // LDS atomic
    }
    __syncthreads();
    int h = hist[t];
    if (h > 0) base[t] = atomicAdd(&bcur[t], h);   // one global atomic per non-empty bucket
    __syncthreads();
    hist[t] = 0;
    __syncthreads();
    for (int e = e0 + t; e < e1; e += 256) {
        int d = dst[e];
        int b = d >> 8;
        int p = base[b] + atomicAdd(&hist[b], 1);
        tmp[p] = (unsigned int)src[e] | ((unsigned int)(d & 255) << 16);
    }
}

// phase B: one block per bucket; per-node LDS cursors; clustered col writes (u16)
__global__ __launch_bounds__(256) void bucket_fill_kernel(const unsigned int* __restrict__ tmp,
                                                          const int* __restrict__ row_ptr,
                                                          unsigned short* __restrict__ col,
                                                          int n, int E) {
    int node0 = blockIdx.x << 8;
    int nn = min(256, n - node0);
    __shared__ int cur[256];
    int t = threadIdx.x;
    if (t < nn) cur[t] = row_ptr[node0 + t];
    __syncthreads();
    int beg = row_ptr[node0];
    int end = row_ptr[node0 + nn];
    for (int i = beg + t; i < end; i += 256) {
        unsigned int v = tmp[i];
        int dlo = (v >> 16) & 255;
        int p = atomicAdd(&cur[dlo], 1);
        col[p] = (unsigned short)(v & 0xFFFFu);
    }
}

// ================= fused layer: mean-aggregate (LDS) + dual MFMA GEMM =================
// 64 nodes/block. Phase 1: quarter-wave (16 lanes) per node, 4 nodes each, agg -> LDS
// (row stride 136 shorts: 2-way bank aliasing only). Phase 2: 4 waves x 16 rows MFMA,
// A(agg) from LDS, A(x) from global, B preswizzled, C epilogue bias(+ReLU).
template <int DOUT, bool RELU, bool OUTBF>
__global__ __launch_bounds__(256, 4) void fused_layer_kernel(
    const unsigned short* __restrict__ feat, const int* __restrict__ row_ptr,
    const unsigned short* __restrict__ col, const unsigned short* __restrict__ Wp,
    const float* __restrict__ bias, void* __restrict__ outv, int n) {
    constexpr int NT = DOUT / 16;
    constexpr int LDA = 136;   // shorts per LDS row (128 + 8 pad)
    __shared__ unsigned short As[64 * LDA];

    const int t = threadIdx.x;
    const int node_base = blockIdx.x * 64;

    // ---- phase 1: aggregate 4 nodes per 16-lane group ----
    {
        const int g = t >> 4;     // group 0..15
        const int gl = t & 15;    // lane in group
        const int fb = gl << 3;   // 8 shorts = 16B per lane
#pragma unroll
        for (int i = 0; i < 4; i++) {
            int local = g * 4 + i;
            int node = node_base + local;
            float a0 = 0.f, a1 = 0.f, a2 = 0.f, a3 = 0.f;
            float a4 = 0.f, a5 = 0.f, a6 = 0.f, a7 = 0.f;
            float sc = 0.f;
            if (node < n) {
                int beg = row_ptr[node], end = row_ptr[node + 1];
                int e = beg;
                for (; e + 1 < end; e += 2) {
                    int c0 = col[e], c1 = col[e + 1];
                    uint4 v0 = *reinterpret_cast<const uint4*>(feat + (size_t)c0 * DIN + fb);
                    uint4 v1 = *reinterpret_cast<const uint4*>(feat + (size_t)c1 * DIN + fb);
                    a0 += bflo(v0.x); a1 += bfhi(v0.x);
                    a2 += bflo(v0.y); a3 += bfhi(v0.y);
                    a4 += bflo(v0.z); a5 += bfhi(v0.z);
                    a6 += bflo(v0.w); a7 += bfhi(v0.w);
                    a0 += bflo(v1.x); a1 += bfhi(v1.x);
                    a2 += bflo(v1.y); a3 += bfhi(v1.y);
                    a4 += bflo(v1.z); a5 += bfhi(v1.z);
                    a6 += bflo(v1.w); a7 += bfhi(v1.w);
                }
                if (e < end) {
                    int c0 = col[e];
                    uint4 v0 = *reinterpret_cast<const uint4*>(feat + (size_t)c0 * DIN + fb);
                    a0 += bflo(v0.x); a1 += bfhi(v0.x);
                    a2 += bflo(v0.y); a3 += bfhi(v0.y);
                    a4 += bflo(v0.z); a5 += bfhi(v0.z);
                    a6 += bflo(v0.w); a7 += bfhi(v0.w);
                }
                sc = 1.0f / fmaxf((float)(end - beg), 1.0f);
            }
            ushort8v o = {f2bf(a0 * sc), f2bf(a1 * sc), f2bf(a2 * sc), f2bf(a3 * sc),
                          f2bf(a4 * sc), f2bf(a5 * sc), f2bf(a6 * sc), f2bf(a7 * sc)};
            *reinterpret_cast<ushort8v*>(&As[local * LDA + fb]) = o;
        }
    }
    __syncthreads();

    // ---- phase 2: dual MFMA GEMM ----
    const int lane = t & 63;
    const int wave = t >> 6;
    const int row0 = node_base + wave * 16;
    const int lrow = wave * 16 + (lane & 15);
    const int ar = node_base + lrow;
    const int kg = (lane >> 4) << 3;
    const bool ok = ar < n;

    const short8 z = {0, 0, 0, 0, 0, 0, 0, 0};
    short8 a[8];
    const unsigned short* lds_row = &As[lrow * LDA + kg];
    const unsigned short* xrow = feat + (size_t)ar * DIN + kg;
#pragma unroll
    for (int ks = 0; ks < 4; ks++)
        a[ks] = *reinterpret_cast<const short8*>(lds_row + ks * 32);
#pragma unroll
    for (int ks = 0; ks < 4; ks++)
        a[4 + ks] = ok ? *reinterpret_cast<const short8*>(xrow + ks * 32) : z;

    f32x4 acc[NT];
#pragma unroll
    for (int nt = 0; nt < NT; nt++) acc[nt] = {0.f, 0.f, 0.f, 0.f};

    const unsigned short* wp = Wp + ((size_t)lane << 3);
#pragma unroll
    for (int nt = 0; nt < NT; nt++) {
#pragma unroll
        for (int ks = 0; ks < 8; ks++) {
            short8 b = *reinterpret_cast<const short8*>(wp + ((size_t)(nt * 8 + ks) << 9));
            acc[nt] = __builtin_amdgcn_mfma_f32_16x16x32_bf16(a[ks], b, acc[nt], 0, 0, 0);
        }
    }

    const int orow0 = row0 + ((lane >> 4) << 2);
#pragma unroll
    for (int nt = 0; nt < NT; nt++) {
        int c = nt * 16 + (lane & 15);
        float bv = bias[c];
#pragma unroll
        for (int rg = 0; rg < 4; rg++) {
            int rr = orow0 + rg;
            if (rr < n) {
                float v = acc[nt][rg] + bv;
                if (RELU) v = fmaxf(v, 0.f);
                if (OUTBF)
                    reinterpret_cast<unsigned short*>(outv)[(size_t)rr * DOUT + c] = f2bf(v);
                else
                    reinterpret_cast<float*>(outv)[(size_t)rr * DOUT + c] = v;
            }
        }
    }
}

extern "C" void kernel_launch(void* const* d_in, const int* in_sizes, int n_in,
                              void* d_out, int out_size, void* d_ws, size_t ws_size,
                              hipStream_t stream) {
    const float* x = (const float*)d_in[0];
    const int* ei = (const int*)d_in[1];
    const float* W1l = (const float*)d_in[2];
    const float* b1 = (const float*)d_in[3];
    const float* W1r = (const float*)d_in[4];
    const float* W2l = (const float*)d_in[5];
    const float* b2 = (const float*)d_in[6];
    const float* W2r = (const float*)d_in[7];
    const float* W3l = (const float*)d_in[8];
    const float* b3 = (const float*)d_in[9];
    const float* W3r = (const float*)d_in[10];
    float* out = (float*)d_out;

    const int n = in_sizes[0] / DIN;   // 50000
    const int E = in_sizes[1] / 2;     // 800000
    const int* src = ei;
    const int* dst = ei + E;

    // ---- workspace layout (256B-aligned sections) ----
    char* p = (char*)d_ws;
    auto take = [&](size_t bytes) {
        char* r = p;
        p += (bytes + 255) & ~(size_t)255;
        return r;
    };
    int* deg = (int*)take((size_t)n * 4);
    int* excl = (int*)take((size_t)n * 4);
    int* bsum = (int*)take(256 * 4);
    int* boff = (int*)take(256 * 4);
    int* row_ptr = (int*)take(((size_t)n + 1) * 4);
    int* bcur = (int*)take(256 * 4);
    unsigned int* tmp = (unsigned int*)take((size_t)E * 4);
    unsigned short* col = (unsigned short*)take((size_t)E * 2);
    unsigned short* xb = (unsigned short*)take((size_t)n * DIN * 2);
    unsigned short* h1b = (unsigned short*)take((size_t)n * DIN * 2);
    unsigned short* h2b = (unsigned short*)take((size_t)n * DIN * 2);
    unsigned short* Wp1 = (unsigned short*)take(128 * 256 * 2);
    unsigned short* Wp2 = (unsigned short*)take(128 * 256 * 2);
    unsigned short* Wp3 = (unsigned short*)take(64 * 256 * 2);

    const int nb_hist = ((E >> 2) + (E & 3) + 255) / 256 + 1;
    const int nb_scan = (n + 255) / 256;         // 196
    const int nb_scan3 = (n + 256) / 256;
    const int nb_gemm = (n + 63) / 64;
    const int nb_cvt = (n * 32 + 255) / 256;
    const int n_buckets = (n + 255) / 256;       // 196
    const int nb_chunk = (E + CHUNK - 1) / CHUNK;

    // ---- conversions (independent of CSR) ----
    convert_x_kernel<<<nb_cvt, 256, 0, stream>>>(x, xb, n * 32);
    pack_w_kernel<128><<<16, 256, 0, stream>>>(W1l, W1r, Wp1);
    pack_w_kernel<128><<<16, 256, 0, stream>>>(W2l, W2r, Wp2);
    pack_w_kernel<64><<<8, 256, 0, stream>>>(W3l, W3r, Wp3);

    // ---- CSR build (binned two-phase fill, block-local histograms) ----
    hipMemsetAsync(deg, 0, (size_t)n * sizeof(int), stream);
    hist_kernel<<<nb_hist, 256, 0, stream>>>(dst, deg, E);
    scan1_kernel<<<nb_scan, 256, 0, stream>>>(deg, excl, bsum, n);
    scan2_kernel<<<1, 256, 0, stream>>>(bsum, boff, nb_scan);
    scan3_kernel<<<nb_scan3, 256, 0, stream>>>(excl, boff, row_ptr, bcur, n, E);
    chunk_scatter_kernel<<<nb_chunk, 256, 0, stream>>>(src, dst, bcur, tmp, E);
    bucket_fill_kernel<<<n_buckets, 256, 0, stream>>>(tmp, row_ptr, col, n, E);

    // ---- fused layers ----
    fused_layer_kernel<128, true, true><<<nb_gemm, 256, 0, stream>>>(
        xb, row_ptr, col, Wp1, b1, h1b, n);
    fused_layer_kernel<128, true, true><<<nb_gemm, 256, 0, stream>>>(
        h1b, row_ptr, col, Wp2, b2, h2b, n);
    fused_layer_kernel<64, false, false><<<nb_gemm, 256, 0, stream>>>(
        h2b, row_ptr, col, Wp3, b3, out, n);
}

// Round 9
// 199.397 us; speedup vs baseline: 1.1967x; 1.1967x over previous
//
#include <hip/hip_runtime.h>
#include <hip/hip_bf16.h>

#define DIN 128

typedef __attribute__((ext_vector_type(8))) short short8;
typedef __attribute__((ext_vector_type(4))) float f32x4;
typedef __attribute__((ext_vector_type(4))) unsigned short ushort4v;
typedef __attribute__((ext_vector_type(8))) unsigned short ushort8v;

__device__ __forceinline__ unsigned short f2bf(float f) {
    unsigned int u = __float_as_uint(f);
    u += 0x7FFFu + ((u >> 16) & 1u);   // RNE
    return (unsigned short)(u >> 16);
}
__device__ __forceinline__ float bflo(unsigned int v) { return __uint_as_float(v << 16); }
__device__ __forceinline__ float bfhi(unsigned int v) { return __uint_as_float(v & 0xFFFF0000u); }

// ================= dtype conversion =================
__global__ __launch_bounds__(256) void convert_x_kernel(const float* __restrict__ x,
                                                        unsigned short* __restrict__ xb,
                                                        int total4) {
    int i = blockIdx.x * 256 + threadIdx.x;
    if (i < total4) {
        float4 v = reinterpret_cast<const float4*>(x)[i];
        ushort4v o = {f2bf(v.x), f2bf(v.y), f2bf(v.z), f2bf(v.w)};
        reinterpret_cast<ushort4v*>(xb)[i] = o;
    }
}

// pack [Wl|Wr] into MFMA-fragment-ordered bf16 (chunk (nt,ks): 64 lanes x 8 bf16)
template <int DOUT>
__global__ __launch_bounds__(256) void pack_w_kernel(const float* __restrict__ Wl,
                                                     const float* __restrict__ Wr,
                                                     unsigned short* __restrict__ Wp) {
    constexpr int NT = DOUT / 16;
    int idx = blockIdx.x * 256 + threadIdx.x;
    if (idx >= NT * 8 * 64) return;
    int l = idx & 63;
    int ts = idx >> 6;
    int ks = ts & 7;
    int nt = ts >> 3;
    int row = nt * 16 + (l & 15);
    int k = ks * 32 + ((l >> 4) << 3);
    const float* s = (k < 128) ? (Wl + (size_t)row * 128 + k)
                               : (Wr + (size_t)row * 128 + (k - 128));
    float4 v0 = *reinterpret_cast<const float4*>(s);
    float4 v1 = *reinterpret_cast<const float4*>(s + 4);
    unsigned short* d = Wp + (size_t)idx * 8;
    ushort4v o0 = {f2bf(v0.x), f2bf(v0.y), f2bf(v0.z), f2bf(v0.w)};
    ushort4v o1 = {f2bf(v1.x), f2bf(v1.y), f2bf(v1.z), f2bf(v1.w)};
    *reinterpret_cast<ushort4v*>(d) = o0;
    *reinterpret_cast<ushort4v*>(d + 4) = o1;
}

// ================= CSR build (bucket b = nodes [b*256, (b+1)*256)) =================
// counters padded: one int per 128B line to avoid cross-XCD line ping-pong
#define PAD 32

__global__ __launch_bounds__(256) void bucket_count_kernel(const int* __restrict__ dst,
                                                           int* __restrict__ bcnt, int E) {
    __shared__ int h[256];
    int t = threadIdx.x;
    h[t] = 0;
    __syncthreads();
    for (int i = blockIdx.x * 256 + t; i < E; i += gridDim.x * 256)
        atomicAdd(&h[dst[i] >> 8], 1);
    __syncthreads();
    if (h[t] > 0) atomicAdd(&bcnt[t * PAD], h[t]);
}

// single block: scan bucket counts -> bbase[0..256], init padded cursors, row_ptr[n]=E
__global__ __launch_bounds__(256) void bucket_scan_kernel(const int* __restrict__ bcnt,
                                                          int* __restrict__ bbase,
                                                          int* __restrict__ bcur,
                                                          int* __restrict__ row_ptr,
                                                          int nb, int n, int E) {
    __shared__ int s[256];
    int t = threadIdx.x;
    int v = (t < nb) ? bcnt[t * PAD] : 0;
    s[t] = v;
    __syncthreads();
    for (int off = 1; off < 256; off <<= 1) {
        int add = (t >= off) ? s[t - off] : 0;
        __syncthreads();
        s[t] += add;
        __syncthreads();
    }
    int excl = s[t] - v;
    bbase[t] = excl;
    bcur[t * PAD] = excl;
    if (t == 255) {
        bbase[256] = s[255];
        row_ptr[n] = E;
    }
}

// phase A: per-block LDS bucket histogram -> one global range-claim per (block,bucket)
#define CHUNK 4096
__global__ __launch_bounds__(256) void chunk_scatter_kernel(const int* __restrict__ src,
                                                            const int* __restrict__ dst,
                                                            int* __restrict__ bcur,
                                                            unsigned int* __restrict__ tmp,
                                                            int E) {
    __shared__ int hist[256];
    __shared__ int base[256];
    int t = threadIdx.x;
    int e0 = blockIdx.x * CHUNK;
    int e1 = min(e0 + CHUNK, E);
    hist[t] = 0;
    __syncthreads();
    for (int e = e0 + t; e < e1; e += 256) {
        atomicAdd(&hist[dst[e] >> 8], 1);   // LDS atomic
    }
    __syncthreads();
    int h = hist[t];
    if (h > 0) base[t] = atomicAdd(&bcur[t * PAD], h);
    __syncthreads();
    hist[t] = 0;
    __syncthreads();
    for (int e = e0 + t; e < e1; e += 256) {
        int d = dst[e];
        int b = d >> 8;
        int p = base[b] + atomicAdd(&hist[b], 1);
        tmp[p] = (unsigned int)src[e] | ((unsigned int)(d & 255) << 16);
    }
}

// phase B: one block per bucket; derive per-node deg + row_ptr locally; write sorted col (u16)
__global__ __launch_bounds__(256) void bucket_fill_kernel(const unsigned int* __restrict__ tmp,
                                                          const int* __restrict__ bbase,
                                                          int* __restrict__ row_ptr,
                                                          unsigned short* __restrict__ col,
                                                          int n) {
    int b = blockIdx.x;
    int node0 = b << 8;
    int nn = min(256, n - node0);
    int begB = bbase[b], endB = bbase[b + 1];
    __shared__ int s[256];
    __shared__ int cur[256];
    int t = threadIdx.x;
    s[t] = 0;
    __syncthreads();
    for (int i = begB + t; i < endB; i += 256)
        atomicAdd(&s[(tmp[i] >> 16) & 255], 1);   // LDS deg histogram
    __syncthreads();
    int v = s[t];
    __syncthreads();
    // inclusive scan of s
    for (int off = 1; off < 256; off <<= 1) {
        int add = (t >= off) ? s[t - off] : 0;
        __syncthreads();
        s[t] += add;
        __syncthreads();
    }
    int r = begB + s[t] - v;   // row start for node node0+t
    if (t < nn) row_ptr[node0 + t] = r;
    cur[t] = r;
    __syncthreads();
    for (int i = begB + t; i < endB; i += 256) {
        unsigned int e = tmp[i];
        int p = atomicAdd(&cur[(e >> 16) & 255], 1);
        col[p] = (unsigned short)(e & 0xFFFFu);
    }
}

// ================= gather-aggregate (mean), bf16 =================
// wave per node; 4 edge slots x 4 loads/iter = 16 outstanding uint4 loads; fp32 accum
__global__ __launch_bounds__(256) void aggregate_kernel(const unsigned short* __restrict__ feat,
                                                        const int* __restrict__ row_ptr,
                                                        const unsigned short* __restrict__ col,
                                                        unsigned short* __restrict__ agg, int n) {
    int node = (blockIdx.x << 2) + (threadIdx.x >> 6);
    if (node >= n) return;
    int lane = threadIdx.x & 63;
    int sub = lane >> 4;          // edge slot 0..3
    int fb = (lane & 15) << 3;    // 8 bf16 = 16B per lane
    int beg = row_ptr[node], end = row_ptr[node + 1];
    float a0 = 0.f, a1 = 0.f, a2 = 0.f, a3 = 0.f, a4 = 0.f, a5 = 0.f, a6 = 0.f, a7 = 0.f;
    int e = beg + sub;
    for (; e + 12 < end; e += 16) {
        int c0 = col[e];
        int c1 = col[e + 4];
        int c2 = col[e + 8];
        int c3 = col[e + 12];
        uint4 v0 = *reinterpret_cast<const uint4*>(feat + (size_t)c0 * DIN + fb);
        uint4 v1 = *reinterpret_cast<const uint4*>(feat + (size_t)c1 * DIN + fb);
        uint4 v2 = *reinterpret_cast<const uint4*>(feat + (size_t)c2 * DIN + fb);
        uint4 v3 = *reinterpret_cast<const uint4*>(feat + (size_t)c3 * DIN + fb);
        a0 += bflo(v0.x); a1 += bfhi(v0.x); a2 += bflo(v0.y); a3 += bfhi(v0.y);
        a4 += bflo(v0.z); a5 += bfhi(v0.z); a6 += bflo(v0.w); a7 += bfhi(v0.w);
        a0 += bflo(v1.x); a1 += bfhi(v1.x); a2 += bflo(v1.y); a3 += bfhi(v1.y);
        a4 += bflo(v1.z); a5 += bfhi(v1.z); a6 += bflo(v1.w); a7 += bfhi(v1.w);
        a0 += bflo(v2.x); a1 += bfhi(v2.x); a2 += bflo(v2.y); a3 += bfhi(v2.y);
        a4 += bflo(v2.z); a5 += bfhi(v2.z); a6 += bflo(v2.w); a7 += bfhi(v2.w);
        a0 += bflo(v3.x); a1 += bfhi(v3.x); a2 += bflo(v3.y); a3 += bfhi(v3.y);
        a4 += bflo(v3.z); a5 += bfhi(v3.z); a6 += bflo(v3.w); a7 += bfhi(v3.w);
    }
    for (; e < end; e += 4) {
        int c0 = col[e];
        uint4 v0 = *reinterpret_cast<const uint4*>(feat + (size_t)c0 * DIN + fb);
        a0 += bflo(v0.x); a1 += bfhi(v0.x); a2 += bflo(v0.y); a3 += bfhi(v0.y);
        a4 += bflo(v0.z); a5 += bfhi(v0.z); a6 += bflo(v0.w); a7 += bfhi(v0.w);
    }
    a0 += __shfl_xor(a0, 16); a1 += __shfl_xor(a1, 16);
    a2 += __shfl_xor(a2, 16); a3 += __shfl_xor(a3, 16);
    a4 += __shfl_xor(a4, 16); a5 += __shfl_xor(a5, 16);
    a6 += __shfl_xor(a6, 16); a7 += __shfl_xor(a7, 16);
    a0 += __shfl_xor(a0, 32); a1 += __shfl_xor(a1, 32);
    a2 += __shfl_xor(a2, 32); a3 += __shfl_xor(a3, 32);
    a4 += __shfl_xor(a4, 32); a5 += __shfl_xor(a5, 32);
    a6 += __shfl_xor(a6, 32); a7 += __shfl_xor(a7, 32);
    if (sub == 0) {
        float sc = 1.0f / fmaxf((float)(end - beg), 1.0f);
        ushort8v o = {f2bf(a0 * sc), f2bf(a1 * sc), f2bf(a2 * sc), f2bf(a3 * sc),
                      f2bf(a4 * sc), f2bf(a5 * sc), f2bf(a6 * sc), f2bf(a7 * sc)};
        *reinterpret_cast<ushort8v*>(agg + (size_t)node * DIN + fb) = o;
    }
}

// ================= MFMA dual GEMM: out = [agg|x] @ Wp^T + b =================
template <int DOUT, bool RELU, bool OUTBF>
__global__ __launch_bounds__(256, 4) void mfma_gemm_kernel(
    const unsigned short* __restrict__ aggb, const unsigned short* __restrict__ xb,
    const unsigned short* __restrict__ Wp, const float* __restrict__ bias,
    void* __restrict__ outv, int n) {
    constexpr int NT = DOUT / 16;
    const int lane = threadIdx.x & 63;
    const int wave = threadIdx.x >> 6;
    const int row0 = blockIdx.x * 64 + wave * 16;
    const int ar = row0 + (lane & 15);
    const int kg = (lane >> 4) << 3;
    const bool ok = ar < n;

    const short8 z = {0, 0, 0, 0, 0, 0, 0, 0};
    short8 a[8];
    const unsigned short* arow = aggb + (size_t)ar * DIN + kg;
    const unsigned short* xrow = xb + (size_t)ar * DIN + kg;
#pragma unroll
    for (int ks = 0; ks < 4; ks++)
        a[ks] = ok ? *reinterpret_cast<const short8*>(arow + ks * 32) : z;
#pragma unroll
    for (int ks = 0; ks < 4; ks++)
        a[4 + ks] = ok ? *reinterpret_cast<const short8*>(xrow + ks * 32) : z;

    f32x4 acc[NT];
#pragma unroll
    for (int nt = 0; nt < NT; nt++) acc[nt] = {0.f, 0.f, 0.f, 0.f};

    const unsigned short* wp = Wp + ((size_t)lane << 3);
#pragma unroll
    for (int nt = 0; nt < NT; nt++) {
#pragma unroll
        for (int ks = 0; ks < 8; ks++) {
            short8 b = *reinterpret_cast<const short8*>(wp + ((size_t)(nt * 8 + ks) << 9));
            acc[nt] = __builtin_amdgcn_mfma_f32_16x16x32_bf16(a[ks], b, acc[nt], 0, 0, 0);
        }
    }

    const int orow0 = row0 + ((lane >> 4) << 2);
#pragma unroll
    for (int nt = 0; nt < NT; nt++) {
        int c = nt * 16 + (lane & 15);
        float bv = bias[c];
#pragma unroll
        for (int rg = 0; rg < 4; rg++) {
            int rr = orow0 + rg;
            if (rr < n) {
                float v = acc[nt][rg] + bv;
                if (RELU) v = fmaxf(v, 0.f);
                if (OUTBF)
                    reinterpret_cast<unsigned short*>(outv)[(size_t)rr * DOUT + c] = f2bf(v);
                else
                    reinterpret_cast<float*>(outv)[(size_t)rr * DOUT + c] = v;
            }
        }
    }
}

extern "C" void kernel_launch(void* const* d_in, const int* in_sizes, int n_in,
                              void* d_out, int out_size, void* d_ws, size_t ws_size,
                              hipStream_t stream) {
    const float* x = (const float*)d_in[0];
    const int* ei = (const int*)d_in[1];
    const float* W1l = (const float*)d_in[2];
    const float* b1 = (const float*)d_in[3];
    const float* W1r = (const float*)d_in[4];
    const float* W2l = (const float*)d_in[5];
    const float* b2 = (const float*)d_in[6];
    const float* W2r = (const float*)d_in[7];
    const float* W3l = (const float*)d_in[8];
    const float* b3 = (const float*)d_in[9];
    const float* W3r = (const float*)d_in[10];
    float* out = (float*)d_out;

    const int n = in_sizes[0] / DIN;   // 50000
    const int E = in_sizes[1] / 2;     // 800000
    const int* src = ei;
    const int* dst = ei + E;

    // ---- workspace layout (256B-aligned sections) ----
    char* p = (char*)d_ws;
    auto take = [&](size_t bytes) {
        char* r = p;
        p += (bytes + 255) & ~(size_t)255;
        return r;
    };
    int* bcnt = (int*)take(256 * PAD * 4);
    int* bcur = (int*)take(256 * PAD * 4);
    int* bbase = (int*)take(257 * 4);
    int* row_ptr = (int*)take(((size_t)n + 1) * 4);
    unsigned int* tmp = (unsigned int*)take((size_t)E * 4);
    unsigned short* col = (unsigned short*)take((size_t)E * 2);
    unsigned short* xb = (unsigned short*)take((size_t)n * DIN * 2);
    unsigned short* aggb = (unsigned short*)take((size_t)n * DIN * 2);
    unsigned short* h1b = (unsigned short*)take((size_t)n * DIN * 2);
    unsigned short* h2b = (unsigned short*)take((size_t)n * DIN * 2);
    unsigned short* Wp1 = (unsigned short*)take(128 * 256 * 2);
    unsigned short* Wp2 = (unsigned short*)take(128 * 256 * 2);
    unsigned short* Wp3 = (unsigned short*)take(64 * 256 * 2);

    const int n_buckets = (n + 255) / 256;       // 196
    const int nb_agg = (n + 3) / 4;
    const int nb_gemm = (n + 63) / 64;
    const int nb_cvt = (n * 32 + 255) / 256;
    const int nb_chunk = (E + CHUNK - 1) / CHUNK;

    // ---- conversions (independent of CSR) ----
    convert_x_kernel<<<nb_cvt, 256, 0, stream>>>(x, xb, n * 32);
    pack_w_kernel<128><<<16, 256, 0, stream>>>(W1l, W1r, Wp1);
    pack_w_kernel<128><<<16, 256, 0, stream>>>(W2l, W2r, Wp2);
    pack_w_kernel<64><<<8, 256, 0, stream>>>(W3l, W3r, Wp3);

    // ---- CSR build ----
    hipMemsetAsync(bcnt, 0, 256 * PAD * 4, stream);
    bucket_count_kernel<<<784, 256, 0, stream>>>(dst, bcnt, E);
    bucket_scan_kernel<<<1, 256, 0, stream>>>(bcnt, bbase, bcur, row_ptr, n_buckets, n, E);
    chunk_scatter_kernel<<<nb_chunk, 256, 0, stream>>>(src, dst, bcur, tmp, E);
    bucket_fill_kernel<<<n_buckets, 256, 0, stream>>>(tmp, bbase, row_ptr, col, n);

    // ---- layer 1 ----
    aggregate_kernel<<<nb_agg, 256, 0, stream>>>(xb, row_ptr, col, aggb, n);
    mfma_gemm_kernel<128, true, true><<<nb_gemm, 256, 0, stream>>>(aggb, xb, Wp1, b1, h1b, n);

    // ---- layer 2 ----
    aggregate_kernel<<<nb_agg, 256, 0, stream>>>(h1b, row_ptr, col, aggb, n);
    mfma_gemm_kernel<128, true, true><<<nb_gemm, 256, 0, stream>>>(aggb, h1b, Wp2, b2, h2b, n);

    // ---- layer 3 (no relu, fp32 out) ----
    aggregate_kernel<<<nb_agg, 256, 0, stream>>>(h2b, row_ptr, col, aggb, n);
    mfma_gemm_kernel<64, false, false><<<nb_gemm, 256, 0, stream>>>(aggb, h2b, Wp3, b3, out, n);
}